// Round 8
// baseline (186.161 us; speedup 1.0000x reference)
//
#include <hip/hip_runtime.h>

typedef short s8v __attribute__((ext_vector_type(8)));
typedef float f4v __attribute__((ext_vector_type(4)));

__device__ __forceinline__ unsigned short f2bf(float f) {
  unsigned u = __float_as_uint(f);
  u = (u + 0x7fffu + ((u >> 16) & 1u)) >> 16;
  return (unsigned short)u;
}
__device__ __forceinline__ float bf2f(unsigned short s) {
  return __uint_as_float(((unsigned)s) << 16);
}

// ---------------------------------------------------------------------------
// Packed-weight region P (ushort offsets):
//   pWis  [0,16384)       Wis   128x128
//   pWos0 [16384,24576)   Wos[0:128]   128x64
//   pWos1 [24576,32768)   Wos[128:256] 128x64
//   pW12  [32768,40960)   Wg1@Wg2      128x64  (computed on the fly)
//   pWo0  [40960,49152)   Wo[0:128]    128x64
//   pWo1  [49152,53248)   Wo[128:192]   64x64
// Fragment order: P[((kc*(NC/16)+ct)*64+lane)*8+j] =
//                 bf16( W[kc*32+(lane>>4)*8+j][ct*16+(lane&15)] )
// ---------------------------------------------------------------------------
__device__ __forceinline__ void pack_one(const float* __restrict__ W,
                                         unsigned short* __restrict__ P,
                                         int NC, int t) {
  const int lane = t & 63;
  const int ct = (t >> 6) % (NC / 16);
  const int kc = (t >> 6) / (NC / 16);
  const int col = ct * 16 + (lane & 15);
  const int krow = kc * 32 + (lane >> 4) * 8;
  unsigned short tmp[8];
#pragma unroll
  for (int j = 0; j < 8; ++j) tmp[j] = f2bf(W[(krow + j) * NC + col]);
  uint4 o;
  o.x = (unsigned)tmp[0] | ((unsigned)tmp[1] << 16);
  o.y = (unsigned)tmp[2] | ((unsigned)tmp[3] << 16);
  o.z = (unsigned)tmp[4] | ((unsigned)tmp[5] << 16);
  o.w = (unsigned)tmp[6] | ((unsigned)tmp[7] << 16);
  reinterpret_cast<uint4*>(P)[t] = o;
}

// 27 blocks: 8 Wis | 4 Wos0 | 4 Wos1 | 4 W12(on-the-fly) | 4 Wo0 | 2 Wo1 | 1 bvec
__global__ __launch_bounds__(256) void pack_all_kernel(
    const float* __restrict__ Wis, const float* __restrict__ Wos,
    const float* __restrict__ Wo, const float* __restrict__ Wg1,
    const float* __restrict__ Wg2, const float* __restrict__ bg1,
    unsigned short* __restrict__ P, float* __restrict__ bvec) {
  const int b = blockIdx.x;
  const int tid = threadIdx.x;
  if (b < 8) {
    pack_one(Wis, P + 0, 128, b * 256 + tid);
  } else if (b < 12) {
    pack_one(Wos, P + 16384, 64, (b - 8) * 256 + tid);
  } else if (b < 16) {
    pack_one(Wos + 128 * 64, P + 24576, 64, (b - 12) * 256 + tid);
  } else if (b < 20) {
    // W12 = Wg1(128x128) @ Wg2(128x64), packed directly
    const int t = (b - 16) * 256 + tid;
    const int lane = t & 63;
    const int ct = (t >> 6) % 4;
    const int kc = (t >> 6) / 4;
    const int col = ct * 16 + (lane & 15);
    const int krow = kc * 32 + (lane >> 4) * 8;
    unsigned short tmp[8];
#pragma unroll
    for (int j = 0; j < 8; ++j) {
      float acc = 0.f;
      for (int k = 0; k < 128; ++k)
        acc = fmaf(Wg1[(krow + j) * 128 + k], Wg2[k * 64 + col], acc);
      tmp[j] = f2bf(acc);
    }
    uint4 o;
    o.x = (unsigned)tmp[0] | ((unsigned)tmp[1] << 16);
    o.y = (unsigned)tmp[2] | ((unsigned)tmp[3] << 16);
    o.z = (unsigned)tmp[4] | ((unsigned)tmp[5] << 16);
    o.w = (unsigned)tmp[6] | ((unsigned)tmp[7] << 16);
    reinterpret_cast<uint4*>(P + 32768)[t] = o;
  } else if (b < 24) {
    pack_one(Wo, P + 40960, 64, (b - 20) * 256 + tid);
  } else if (b < 26) {
    pack_one(Wo + 128 * 64, P + 49152, 64, (b - 24) * 256 + tid);
  } else if (tid < 64) {
    float acc = 0.f;
    for (int k = 0; k < 128; ++k) acc = fmaf(bg1[k], Wg2[k * 64 + tid], acc);
    bvec[tid] = acc;
  }
}

// ---------------------------------------------------------------------------
// Fused self branch + GCN input transform.  Per block: 4 waves, 64 rows.
// P1: h = relu(x@Wis + bis) -> per-wave swizzled LDS tile (16x128 bf16)
// P2: out1 = x@Wos0 + h@Wos1 + bos (f32);  S2 = x@W12 (bf16)
// ---------------------------------------------------------------------------
__global__ __launch_bounds__(256) void fused_self_kernel(
    const float* __restrict__ x, const unsigned short* __restrict__ P,
    const float* __restrict__ bis, const float* __restrict__ bos,
    float* __restrict__ out1, unsigned short* __restrict__ S2) {
  __shared__ unsigned short Bs[24576];      // 48 KB staging
  __shared__ unsigned short hs[4][2048];    // 16 KB h tiles (per wave 16x128)
  const int tid = threadIdx.x;
  const int wave = tid >> 6;
  const int lane = tid & 63;
  const int row0 = blockIdx.x * 64 + wave * 16;
  const int arow = row0 + (lane & 15);
  const int koff = (lane >> 4) * 8;
  const int rl = lane & 15;

  // x A-fragments (f32 -> bf16 in-register)
  s8v a1[4];
#pragma unroll
  for (int kc = 0; kc < 4; ++kc) {
    const float4 f0 = *reinterpret_cast<const float4*>(
        x + (long long)arow * 128 + kc * 32 + koff);
    const float4 f1 = *reinterpret_cast<const float4*>(
        x + (long long)arow * 128 + kc * 32 + koff + 4);
    s8v r;
    r[0] = (short)f2bf(f0.x); r[1] = (short)f2bf(f0.y);
    r[2] = (short)f2bf(f0.z); r[3] = (short)f2bf(f0.w);
    r[4] = (short)f2bf(f1.x); r[5] = (short)f2bf(f1.y);
    r[6] = (short)f2bf(f1.z); r[7] = (short)f2bf(f1.w);
    a1[kc] = r;
  }

  {  // stage Wis (2048 uint4)
    uint4* d = reinterpret_cast<uint4*>(Bs);
    const uint4* s = reinterpret_cast<const uint4*>(P);
    for (int i = tid; i < 2048; i += 256) d[i] = s[i];
  }
  __syncthreads();

  f4v hacc[8] = {};
#pragma unroll
  for (int kc = 0; kc < 4; ++kc) {
#pragma unroll
    for (int ct = 0; ct < 8; ++ct) {
      const s8v b =
          *reinterpret_cast<const s8v*>(&Bs[((kc * 8 + ct) * 64 + lane) * 8]);
      hacc[ct] = __builtin_amdgcn_mfma_f32_16x16x32_bf16(a1[kc], b, hacc[ct], 0, 0, 0);
    }
  }

  // h epilogue: bias+relu, bf16, swizzled store (col ^= (row&7)<<3)
  const int hrow = (lane >> 4) * 4;
#pragma unroll
  for (int ct = 0; ct < 8; ++ct) {
    const int col = ct * 16 + rl;
    const float bv = bis[col];
#pragma unroll
    for (int r = 0; r < 4; ++r) {
      const int rr = hrow + r;
      const float v = fmaxf(hacc[ct][r] + bv, 0.f);
      hs[wave][rr * 128 + (col ^ ((rr & 7) << 3))] = f2bf(v);
    }
  }
  __syncthreads();

  {  // stage Wos0|Wos1|W12 (3072 uint4, contiguous at P+16384)
    uint4* d = reinterpret_cast<uint4*>(Bs);
    const uint4* s = reinterpret_cast<const uint4*>(P + 16384);
    for (int i = tid; i < 3072; i += 256) d[i] = s[i];
  }
  __syncthreads();

  // h A-fragments from swizzled LDS
  s8v hf[4];
#pragma unroll
  for (int kc = 0; kc < 4; ++kc) {
    const int c0 = kc * 32 + koff;
    const int grp = (c0 >> 3) ^ (rl & 7);
    hf[kc] = *reinterpret_cast<const s8v*>(&hs[wave][rl * 128 + grp * 8]);
  }

  f4v o1[4] = {}, s2[4] = {};
#pragma unroll
  for (int kc = 0; kc < 4; ++kc) {
#pragma unroll
    for (int ct = 0; ct < 4; ++ct) {
      const int fo = ((kc * 4 + ct) * 64 + lane) * 8;
      const s8v b0 = *reinterpret_cast<const s8v*>(&Bs[fo]);
      o1[ct] = __builtin_amdgcn_mfma_f32_16x16x32_bf16(a1[kc], b0, o1[ct], 0, 0, 0);
      const s8v b1 = *reinterpret_cast<const s8v*>(&Bs[8192 + fo]);
      o1[ct] = __builtin_amdgcn_mfma_f32_16x16x32_bf16(hf[kc], b1, o1[ct], 0, 0, 0);
      const s8v b2 = *reinterpret_cast<const s8v*>(&Bs[16384 + fo]);
      s2[ct] = __builtin_amdgcn_mfma_f32_16x16x32_bf16(a1[kc], b2, s2[ct], 0, 0, 0);
    }
  }

  const int crow0 = row0 + hrow;
#pragma unroll
  for (int ct = 0; ct < 4; ++ct) {
    const int col = ct * 16 + rl;
    const float bv = bos[col];
#pragma unroll
    for (int r = 0; r < 4; ++r) {
      out1[(long long)(crow0 + r) * 64 + col] = o1[ct][r] + bv;
      S2[(long long)(crow0 + r) * 64 + col] = f2bf(s2[ct][r]);
    }
  }
}

// ---------------------------------------------------------------------------
// Final GEMM: out2 = x_nb(f32)@Wo0 + g2(bf16)@Wo1 + bo   (f32 out)
// ---------------------------------------------------------------------------
__global__ __launch_bounds__(256) void out2_gemm_kernel(
    const float* __restrict__ A1f, const unsigned short* __restrict__ A2,
    const unsigned short* __restrict__ P1, const unsigned short* __restrict__ P2,
    const float* __restrict__ bias, float* __restrict__ Cout) {
  __shared__ unsigned short Bs[12288];  // 8192 Wo0 + 4096 Wo1

  {
    uint4* d = reinterpret_cast<uint4*>(Bs);
    const uint4* s1 = reinterpret_cast<const uint4*>(P1);
    for (int i = threadIdx.x; i < 1024; i += 256) d[i] = s1[i];
    const uint4* s2 = reinterpret_cast<const uint4*>(P2);
    for (int i = threadIdx.x; i < 512; i += 256) d[1024 + i] = s2[i];
  }

  const int wave = threadIdx.x >> 6;
  const int lane = threadIdx.x & 63;
  const int row0 = blockIdx.x * 64 + wave * 16;
  const int arow = row0 + (lane & 15);
  const int koff = (lane >> 4) * 8;

  s8v a1[4];
#pragma unroll
  for (int kc = 0; kc < 4; ++kc) {
    const float4 f0 = *reinterpret_cast<const float4*>(
        A1f + (long long)arow * 128 + kc * 32 + koff);
    const float4 f1 = *reinterpret_cast<const float4*>(
        A1f + (long long)arow * 128 + kc * 32 + koff + 4);
    s8v r;
    r[0] = (short)f2bf(f0.x); r[1] = (short)f2bf(f0.y);
    r[2] = (short)f2bf(f0.z); r[3] = (short)f2bf(f0.w);
    r[4] = (short)f2bf(f1.x); r[5] = (short)f2bf(f1.y);
    r[6] = (short)f2bf(f1.z); r[7] = (short)f2bf(f1.w);
    a1[kc] = r;
  }
  s8v a2[2];
#pragma unroll
  for (int kc = 0; kc < 2; ++kc)
    a2[kc] = *reinterpret_cast<const s8v*>(A2 + (long long)arow * 64 + kc * 32 + koff);

  __syncthreads();

  f4v acc[4] = {};
#pragma unroll
  for (int kc = 0; kc < 4; ++kc) {
#pragma unroll
    for (int ct = 0; ct < 4; ++ct) {
      const s8v b =
          *reinterpret_cast<const s8v*>(&Bs[((kc * 4 + ct) * 64 + lane) * 8]);
      acc[ct] = __builtin_amdgcn_mfma_f32_16x16x32_bf16(a1[kc], b, acc[ct], 0, 0, 0);
    }
  }
#pragma unroll
  for (int kc = 0; kc < 2; ++kc) {
#pragma unroll
    for (int ct = 0; ct < 4; ++ct) {
      const s8v b = *reinterpret_cast<const s8v*>(
          &Bs[8192 + ((kc * 4 + ct) * 64 + lane) * 8]);
      acc[ct] = __builtin_amdgcn_mfma_f32_16x16x32_bf16(a2[kc], b, acc[ct], 0, 0, 0);
    }
  }

  const int crow0 = row0 + (lane >> 4) * 4;
  const int ccol = lane & 15;
#pragma unroll
  for (int ct = 0; ct < 4; ++ct) {
    const int col = ct * 16 + ccol;
    const float bv = bias[col];
#pragma unroll
    for (int r = 0; r < 4; ++r)
      Cout[(long long)(crow0 + r) * 64 + col] = acc[ct][r] + bv;
  }
}

// ---------------------------------------------------------------------------
// CSR build
// ---------------------------------------------------------------------------
__global__ __launch_bounds__(256) void deg_kernel(
    const int* __restrict__ cols, int* __restrict__ deg, int E) {
  const int i = blockIdx.x * 256 + threadIdx.x;
  if (i < E) atomicAdd(&deg[cols[i]], 1);
}

__global__ __launch_bounds__(1024) void scan1_kernel(
    const int* __restrict__ deg, int* __restrict__ off, int* __restrict__ part,
    float* __restrict__ dis, int N) {
  __shared__ int s[1024];
  const int tid = threadIdx.x;
  const int i = blockIdx.x * 1024 + tid;
  const int v = (i < N) ? deg[i] : 0;
  if (i < N) dis[i] = rsqrtf((float)v + 1.0f);
  s[tid] = v;
  __syncthreads();
  for (int o = 1; o < 1024; o <<= 1) {
    const int t = (tid >= o) ? s[tid - o] : 0;
    __syncthreads();
    s[tid] += t;
    __syncthreads();
  }
  if (i < N) off[i] = s[tid] - v;
  if (tid == 1023) part[blockIdx.x] = s[1023];
}

__global__ __launch_bounds__(1024) void scan3_kernel(
    int* __restrict__ off, const int* __restrict__ part, int N) {
  __shared__ int pp;
  if (threadIdx.x < 64) {
    int v = (threadIdx.x < blockIdx.x) ? part[threadIdx.x] : 0;
#pragma unroll
    for (int o = 32; o > 0; o >>= 1) v += __shfl_down(v, o, 64);
    if (threadIdx.x == 0) pp = v;
  }
  __syncthreads();
  const int i = blockIdx.x * 1024 + threadIdx.x;
  if (i < N) off[i] += pp;
}

// csr[pos] = (src, w = dis[src]*dis[dst]).  Afterwards off[c] = END of seg c.
__global__ __launch_bounds__(256) void fill_kernel(
    const int* __restrict__ rows, const int* __restrict__ cols,
    int* __restrict__ off, const float* __restrict__ dis,
    int2* __restrict__ csr, int E) {
  const int i = blockIdx.x * 256 + threadIdx.x;
  if (i < E) {
    const int c = cols[i];
    const int r = rows[i];
    const int pos = atomicAdd(&off[c], 1);
    int2 e;
    e.x = r;
    e.y = __float_as_int(dis[r] * dis[c]);
    csr[pos] = e;
  }
}

// ---------------------------------------------------------------------------
// D=64 CSR gather, grid-stride waves, 8-deep unroll.
// Pass A: out[n]=A·h (bf16), s_out[n]=Σw+dn² (row-sum of A).
// Pass B: out[n]=A·h + s_in[n]*bvec + bias (bf16).
// ---------------------------------------------------------------------------
template <bool PASS_B>
__global__ __launch_bounds__(256) void gather64_kernel(
    const unsigned short* __restrict__ h, const int2* __restrict__ csr,
    const int* __restrict__ off, const float* __restrict__ dis,
    float* __restrict__ s_out, const float* __restrict__ s_in,
    const float* __restrict__ bvec, const float* __restrict__ bias,
    unsigned short* __restrict__ out, int N) {
  const int gw = (blockIdx.x * 256 + threadIdx.x) >> 6;
  const int lane = threadIdx.x & 63;
  const int nw = gridDim.x * 4;
  const float bb = PASS_B ? bias[lane] : 0.f;
  const float bvl = PASS_B ? bvec[lane] : 0.f;

  for (int n = gw; n < N; n += nw) {
    const float dn = dis[n];
    const float dn2 = dn * dn;
    float a0 = bf2f(h[(long long)n * 64 + lane]) * dn2;
    float sw = dn2;
    const int start = (n == 0) ? 0 : off[n - 1];
    const int end = off[n];
    int j = start;
    for (; j + 7 < end; j += 8) {
      int2 p[8];
#pragma unroll
      for (int q = 0; q < 8; ++q) p[q] = csr[j + q];
      float v[8];
#pragma unroll
      for (int q = 0; q < 8; ++q)
        v[q] = bf2f(h[(long long)p[q].x * 64 + lane]);
#pragma unroll
      for (int q = 0; q < 8; ++q) {
        const float w = __int_as_float(p[q].y);
        a0 = fmaf(v[q], w, a0);
        if constexpr (!PASS_B) sw += w;
      }
    }
    for (; j < end; ++j) {
      const int2 p = csr[j];
      a0 = fmaf(bf2f(h[(long long)p.x * 64 + lane]), __int_as_float(p.y), a0);
      if constexpr (!PASS_B) sw += __int_as_float(p.y);
    }
    if constexpr (!PASS_B) {
      if (lane == 0) s_out[n] = sw;
      out[(long long)n * 64 + lane] = f2bf(a0);
    } else {
      out[(long long)n * 64 + lane] = f2bf(fmaf(s_in[n], bvl, a0 + bb));
    }
  }
}

extern "C" void kernel_launch(void* const* d_in, const int* in_sizes, int n_in,
                              void* d_out, int out_size, void* d_ws,
                              size_t ws_size, hipStream_t stream) {
  const float* x_self = (const float*)d_in[0];
  const float* x_nb = (const float*)d_in[1];
  const int* ei = (const int*)d_in[2];
  const float* Wis = (const float*)d_in[3];
  const float* bis = (const float*)d_in[4];
  const float* Wos = (const float*)d_in[5];
  const float* bos = (const float*)d_in[6];
  const float* Wg1 = (const float*)d_in[7];
  const float* bg1 = (const float*)d_in[8];
  const float* Wg2 = (const float*)d_in[9];
  const float* bg2 = (const float*)d_in[10];
  const float* Wo = (const float*)d_in[11];
  const float* bo = (const float*)d_in[12];

  const int N = in_sizes[0] / 128;
  const int E = (int)(in_sizes[2] / 2);
  const int* rows = ei;
  const int* cols = ei + E;

  float* out1 = (float*)d_out;
  float* out2 = out1 + (long long)N * 64;

  // ws (4B units): dis[N] | deg[N] | off[N+16] | part[64] | s[N] | bvec[64] |
  //   csr int2[E] | S2 bf16[N*64] | S3 bf16[N*64] | G2 bf16[N*64] | P[53248]
  float* dis = (float*)d_ws;
  int* deg = (int*)(dis + N);
  int* off = deg + N;
  int* part = off + N + 16;
  float* s = (float*)(part + 64);
  float* bvec = s + N;
  int2* csr = (int2*)(bvec + 64);
  unsigned short* S2 = (unsigned short*)(csr + E);
  unsigned short* S3 = S2 + (long long)N * 64;
  unsigned short* G2 = S3 + (long long)N * 64;
  unsigned short* P = G2 + (long long)N * 64;
  unsigned short* pWo0 = P + 40960;
  unsigned short* pWo1 = P + 49152;

  const int NB = (N + 1023) / 1024;
  const int GB = N / 64;   // 625
  const int GGB = 2048;    // gather blocks

  // --- CSR build + norms ---
  hipMemsetAsync(deg, 0, (size_t)N * sizeof(int), stream);
  deg_kernel<<<(E + 255) / 256, 256, 0, stream>>>(cols, deg, E);
  scan1_kernel<<<NB, 1024, 0, stream>>>(deg, off, part, dis, N);
  scan3_kernel<<<NB, 1024, 0, stream>>>(off, part, N);
  fill_kernel<<<(E + 255) / 256, 256, 0, stream>>>(rows, cols, off, dis, csr, E);

  // --- weight prep (single dispatch) ---
  pack_all_kernel<<<27, 256, 0, stream>>>(Wis, Wos, Wo, Wg1, Wg2, bg1, P, bvec);

  // --- fused self branch + GCN transform: out1, S2 = x@W12 ---
  fused_self_kernel<<<GB, 256, 0, stream>>>(x_self, P, bis, bos, out1, S2);

  // --- GCN aggregations: g2 = A·(A·S2) + s·bvec + bg2 ---
  gather64_kernel<false><<<GGB, 256, 0, stream>>>(
      S2, csr, off, dis, s, nullptr, nullptr, nullptr, S3, N);
  gather64_kernel<true><<<GGB, 256, 0, stream>>>(
      S3, csr, off, dis, nullptr, s, bvec, bg2, G2, N);

  // --- out2 = x_nb@Wo0 + g2@Wo1 + bo ---
  out2_gemm_kernel<<<GB, 256, 0, stream>>>(x_nb, G2, pWo0, pWo1, bo, out2);
}

// Round 9
// 159.087 us; speedup vs baseline: 1.1702x; 1.1702x over previous
//
#include <hip/hip_runtime.h>

typedef short s8v __attribute__((ext_vector_type(8)));
typedef float f4v __attribute__((ext_vector_type(4)));

__device__ __forceinline__ unsigned short f2bf(float f) {
  unsigned u = __float_as_uint(f);
  u = (u + 0x7fffu + ((u >> 16) & 1u)) >> 16;
  return (unsigned short)u;
}
__device__ __forceinline__ float bf2f(unsigned short s) {
  return __uint_as_float(((unsigned)s) << 16);
}

// ---------------------------------------------------------------------------
__global__ __launch_bounds__(256) void zero_kernel(int* __restrict__ p, int n) {
  const int i = blockIdx.x * 256 + threadIdx.x;
  if (i < n) p[i] = 0;
}

// f32 -> bf16, 4 elems/thread
__global__ __launch_bounds__(256) void cvt_kernel(
    const float* __restrict__ in, unsigned short* __restrict__ out, int n4) {
  const int i = blockIdx.x * 256 + threadIdx.x;
  if (i >= n4) return;
  const float4 v = reinterpret_cast<const float4*>(in)[i];
  ushort4 o;
  o.x = f2bf(v.x); o.y = f2bf(v.y); o.z = f2bf(v.z); o.w = f2bf(v.w);
  reinterpret_cast<ushort4*>(out)[i] = o;
}

// ---------------------------------------------------------------------------
// W12f = Wg1(128x128) @ Wg2(128x64) in f32; bvec = bg1 @ Wg2.
// ---------------------------------------------------------------------------
__global__ __launch_bounds__(256) void w12_kernel(
    const float* __restrict__ W1, const float* __restrict__ W2,
    const float* __restrict__ b1, float* __restrict__ W12f,
    float* __restrict__ bvec) {
  const int b = blockIdx.x;
  if (b < 32) {
    const int t = b * 256 + threadIdx.x;  // t = i*64 + j
    const int i = t >> 6, j = t & 63;
    float acc = 0.f;
    for (int k = 0; k < 128; ++k)
      acc = fmaf(W1[i * 128 + k], W2[k * 64 + j], acc);
    W12f[t] = acc;
  } else if (threadIdx.x < 64) {
    const int j = threadIdx.x;
    float acc = 0.f;
    for (int k = 0; k < 128; ++k) acc = fmaf(b1[k], W2[k * 64 + j], acc);
    bvec[j] = acc;
  }
}

// ---------------------------------------------------------------------------
// Pack weights into MFMA B-fragment order:
// P[((kc*(NC/16)+ct)*64+lane)*8+j] = bf16( W[kc*32+(lane>>4)*8+j][ct*16+(lane&15)] )
// ---------------------------------------------------------------------------
__device__ __forceinline__ void pack_one(const float* __restrict__ W,
                                         unsigned short* __restrict__ P,
                                         int NC, int t) {
  const int lane = t & 63;
  const int ct = (t >> 6) % (NC / 16);
  const int kc = (t >> 6) / (NC / 16);
  const int col = ct * 16 + (lane & 15);
  const int krow = kc * 32 + (lane >> 4) * 8;
  unsigned short tmp[8];
#pragma unroll
  for (int j = 0; j < 8; ++j) tmp[j] = f2bf(W[(krow + j) * NC + col]);
  uint4 o;
  o.x = (unsigned)tmp[0] | ((unsigned)tmp[1] << 16);
  o.y = (unsigned)tmp[2] | ((unsigned)tmp[3] << 16);
  o.z = (unsigned)tmp[4] | ((unsigned)tmp[5] << 16);
  o.w = (unsigned)tmp[6] | ((unsigned)tmp[7] << 16);
  reinterpret_cast<uint4*>(P)[t] = o;
}

// 26 blocks: 8 Wis | 4 Wos0 | 4 Wos1 | 4 Wo0 | 2 Wo1 | 4 W12
__global__ __launch_bounds__(256) void pack_all_kernel(
    const float* __restrict__ Wis, const float* __restrict__ Wos,
    const float* __restrict__ Wo, const float* __restrict__ W12f,
    unsigned short* __restrict__ P) {
  const int b = blockIdx.x;
  const int tid = threadIdx.x;
  if (b < 8)        pack_one(Wis,            P + 0,     128, b * 256 + tid);
  else if (b < 12)  pack_one(Wos,            P + 16384, 64,  (b - 8) * 256 + tid);
  else if (b < 16)  pack_one(Wos + 128 * 64, P + 24576, 64,  (b - 12) * 256 + tid);
  else if (b < 20)  pack_one(Wo,             P + 32768, 64,  (b - 16) * 256 + tid);
  else if (b < 22)  pack_one(Wo + 128 * 64,  P + 40960, 64,  (b - 20) * 256 + tid);
  else              pack_one(W12f,           P + 45056, 64,  (b - 22) * 256 + tid);
}

// ---------------------------------------------------------------------------
// MFMA GEMM: C = A1[M x K1] @ B1 (+ A2[M x K2] @ B2) + bias, optional relu.
// A1 bf16 row-major, or f32 row-major if A1F32 (converted in-register).
// B* pre-packed fragment-order bf16 staged in LDS. M % 64 == 0.
// ---------------------------------------------------------------------------
template <int K1, int K2, int NC, bool RELU, bool OUT_BF16, bool A1F32>
__global__ __launch_bounds__(256) void mfma_gemm_kernel(
    const void* __restrict__ A1v, const unsigned short* __restrict__ A2,
    const unsigned short* __restrict__ P1, const unsigned short* __restrict__ P2,
    const float* __restrict__ bias, void* __restrict__ Cout) {
  constexpr int NT = NC / 16;
  constexpr int KC1 = K1 / 32;
  constexpr int KC2 = (K2 > 0) ? (K2 / 32) : 1;
  __shared__ unsigned short Bs[(K1 + K2) * NC];

  {
    uint4* d = reinterpret_cast<uint4*>(Bs);
    constexpr int n1 = K1 * NC / 8;
    const uint4* s1 = reinterpret_cast<const uint4*>(P1);
    for (int i = threadIdx.x; i < n1; i += 256) d[i] = s1[i];
    if constexpr (K2 > 0) {
      constexpr int n2 = K2 * NC / 8;
      const uint4* s2 = reinterpret_cast<const uint4*>(P2);
      for (int i = threadIdx.x; i < n2; i += 256) d[n1 + i] = s2[i];
    }
  }

  const int wave = threadIdx.x >> 6;
  const int lane = threadIdx.x & 63;
  const int row0 = blockIdx.x * 64 + wave * 16;
  const int arow = row0 + (lane & 15);
  const int koff = (lane >> 4) * 8;

  s8v a1[KC1];
  if constexpr (A1F32) {
    const float* A1f = (const float*)A1v;
#pragma unroll
    for (int kc = 0; kc < KC1; ++kc) {
      const float4 f0 = *reinterpret_cast<const float4*>(
          A1f + (long long)arow * K1 + kc * 32 + koff);
      const float4 f1 = *reinterpret_cast<const float4*>(
          A1f + (long long)arow * K1 + kc * 32 + koff + 4);
      s8v r;
      r[0] = (short)f2bf(f0.x); r[1] = (short)f2bf(f0.y);
      r[2] = (short)f2bf(f0.z); r[3] = (short)f2bf(f0.w);
      r[4] = (short)f2bf(f1.x); r[5] = (short)f2bf(f1.y);
      r[6] = (short)f2bf(f1.z); r[7] = (short)f2bf(f1.w);
      a1[kc] = r;
    }
  } else {
    const unsigned short* A1b = (const unsigned short*)A1v;
#pragma unroll
    for (int kc = 0; kc < KC1; ++kc)
      a1[kc] = *reinterpret_cast<const s8v*>(A1b + (long long)arow * K1 +
                                             kc * 32 + koff);
  }
  s8v a2[KC2];
  if constexpr (K2 > 0) {
#pragma unroll
    for (int kc = 0; kc < K2 / 32; ++kc)
      a2[kc] = *reinterpret_cast<const s8v*>(A2 + (long long)arow * K2 +
                                             kc * 32 + koff);
  }

  __syncthreads();

  f4v acc[NT] = {};
#pragma unroll
  for (int kc = 0; kc < KC1; ++kc) {
#pragma unroll
    for (int ct = 0; ct < NT; ++ct) {
      const s8v b =
          *reinterpret_cast<const s8v*>(&Bs[((kc * NT + ct) * 64 + lane) * 8]);
      acc[ct] = __builtin_amdgcn_mfma_f32_16x16x32_bf16(a1[kc], b, acc[ct], 0, 0, 0);
    }
  }
  if constexpr (K2 > 0) {
#pragma unroll
    for (int kc = 0; kc < K2 / 32; ++kc) {
#pragma unroll
      for (int ct = 0; ct < NT; ++ct) {
        const s8v b = *reinterpret_cast<const s8v*>(
            &Bs[(((KC1 + kc) * NT + ct) * 64 + lane) * 8]);
        acc[ct] = __builtin_amdgcn_mfma_f32_16x16x32_bf16(a2[kc], b, acc[ct], 0, 0, 0);
      }
    }
  }

  const int crow0 = row0 + (lane >> 4) * 4;
  const int ccol = lane & 15;
#pragma unroll
  for (int ct = 0; ct < NT; ++ct) {
    const int col = ct * 16 + ccol;
    const float bv = bias ? bias[col] : 0.f;
#pragma unroll
    for (int r = 0; r < 4; ++r) {
      float v = acc[ct][r] + bv;
      if (RELU) v = fmaxf(v, 0.f);
      const long long idx = (long long)(crow0 + r) * NC + col;
      if (OUT_BF16)
        ((unsigned short*)Cout)[idx] = f2bf(v);
      else
        ((float*)Cout)[idx] = v;
    }
  }
}

// ---------------------------------------------------------------------------
// CSR build
// ---------------------------------------------------------------------------
__global__ __launch_bounds__(256) void deg_kernel(
    const int* __restrict__ cols, int* __restrict__ deg, int E) {
  const int i = blockIdx.x * 256 + threadIdx.x;
  if (i < E) atomicAdd(&deg[cols[i]], 1);
}

__global__ __launch_bounds__(1024) void scan1_kernel(
    const int* __restrict__ deg, int* __restrict__ off, int* __restrict__ part,
    float* __restrict__ dis, int N) {
  __shared__ int s[1024];
  const int tid = threadIdx.x;
  const int i = blockIdx.x * 1024 + tid;
  const int v = (i < N) ? deg[i] : 0;
  if (i < N) dis[i] = rsqrtf((float)v + 1.0f);
  s[tid] = v;
  __syncthreads();
  for (int o = 1; o < 1024; o <<= 1) {
    const int t = (tid >= o) ? s[tid - o] : 0;
    __syncthreads();
    s[tid] += t;
    __syncthreads();
  }
  if (i < N) off[i] = s[tid] - v;
  if (tid == 1023) part[blockIdx.x] = s[1023];
}

__global__ __launch_bounds__(1024) void scan3_kernel(
    int* __restrict__ off, const int* __restrict__ part, int N) {
  __shared__ int pp;
  if (threadIdx.x < 64) {
    int v = (threadIdx.x < blockIdx.x) ? part[threadIdx.x] : 0;
#pragma unroll
    for (int o = 32; o > 0; o >>= 1) v += __shfl_down(v, o, 64);
    if (threadIdx.x == 0) pp = v;
  }
  __syncthreads();
  const int i = blockIdx.x * 1024 + threadIdx.x;
  if (i < N) off[i] += pp;
}

// csr[pos] = (src, w = dis[src]*dis[dst]).  Afterwards off[c] = END of seg c.
__global__ __launch_bounds__(256) void fill_kernel(
    const int* __restrict__ rows, const int* __restrict__ cols,
    int* __restrict__ off, const float* __restrict__ dis,
    int2* __restrict__ csr, int E) {
  const int i = blockIdx.x * 256 + threadIdx.x;
  if (i < E) {
    const int c = cols[i];
    const int r = rows[i];
    const int pos = atomicAdd(&off[c], 1);
    int2 e;
    e.x = r;
    e.y = __float_as_int(dis[r] * dis[c]);
    csr[pos] = e;
  }
}

// ---------------------------------------------------------------------------
// D=64 CSR gather, 4 nodes per wave (16-lane groups, ushort4/lane), 4-unroll.
// Group g of a wave owns node wid*4+g: 4 independent edge chains per wave ->
// 4x memory-level parallelism, serial depth = max(deg) not sum(deg).
// Pass A: out[n]=A·h (bf16), s_out[n]=Σw+dn² (row-sum of A).
// Pass B: out[n]=A·h + s_in[n]*bvec + bias (bf16).
// ---------------------------------------------------------------------------
template <bool PASS_B>
__global__ __launch_bounds__(256) void gather64_kernel(
    const unsigned short* __restrict__ h, const int2* __restrict__ csr,
    const int* __restrict__ off, const float* __restrict__ dis,
    float* __restrict__ s_out, const float* __restrict__ s_in,
    const float* __restrict__ bvec, const float* __restrict__ bias,
    unsigned short* __restrict__ out, int N) {
  const int wid = (blockIdx.x * 256 + threadIdx.x) >> 6;
  const int lane = threadIdx.x & 63;
  const int grp = lane >> 4;   // node slot within wave
  const int sl = lane & 15;    // feature slot (4 features each)
  const int stride = gridDim.x * 16;

  float bb0 = 0.f, bb1 = 0.f, bb2 = 0.f, bb3 = 0.f;
  float bv0 = 0.f, bv1 = 0.f, bv2 = 0.f, bv3 = 0.f;
  if constexpr (PASS_B) {
    const float4 b4 = *reinterpret_cast<const float4*>(bias + sl * 4);
    bb0 = b4.x; bb1 = b4.y; bb2 = b4.z; bb3 = b4.w;
    const float4 v4 = *reinterpret_cast<const float4*>(bvec + sl * 4);
    bv0 = v4.x; bv1 = v4.y; bv2 = v4.z; bv3 = v4.w;
  }

  for (int n = wid * 4 + grp; n < N; n += stride) {
    const float dn = dis[n];
    const float dn2 = dn * dn;
    const ushort4 hv =
        *reinterpret_cast<const ushort4*>(h + (long long)n * 64 + sl * 4);
    float a0 = bf2f(hv.x) * dn2, a1 = bf2f(hv.y) * dn2;
    float a2 = bf2f(hv.z) * dn2, a3 = bf2f(hv.w) * dn2;
    float sw = dn2;
    const int start = (n == 0) ? 0 : off[n - 1];
    const int end = off[n];
    int j = start;
    for (; j + 3 < end; j += 4) {
      const int2 p0 = csr[j], p1 = csr[j + 1], p2 = csr[j + 2], p3 = csr[j + 3];
      const ushort4 u0 =
          *reinterpret_cast<const ushort4*>(h + (long long)p0.x * 64 + sl * 4);
      const ushort4 u1 =
          *reinterpret_cast<const ushort4*>(h + (long long)p1.x * 64 + sl * 4);
      const ushort4 u2 =
          *reinterpret_cast<const ushort4*>(h + (long long)p2.x * 64 + sl * 4);
      const ushort4 u3 =
          *reinterpret_cast<const ushort4*>(h + (long long)p3.x * 64 + sl * 4);
      const float w0 = __int_as_float(p0.y), w1 = __int_as_float(p1.y);
      const float w2 = __int_as_float(p2.y), w3 = __int_as_float(p3.y);
      a0 = fmaf(bf2f(u0.x), w0, a0); a1 = fmaf(bf2f(u0.y), w0, a1);
      a2 = fmaf(bf2f(u0.z), w0, a2); a3 = fmaf(bf2f(u0.w), w0, a3);
      a0 = fmaf(bf2f(u1.x), w1, a0); a1 = fmaf(bf2f(u1.y), w1, a1);
      a2 = fmaf(bf2f(u1.z), w1, a2); a3 = fmaf(bf2f(u1.w), w1, a3);
      a0 = fmaf(bf2f(u2.x), w2, a0); a1 = fmaf(bf2f(u2.y), w2, a1);
      a2 = fmaf(bf2f(u2.z), w2, a2); a3 = fmaf(bf2f(u2.w), w2, a3);
      a0 = fmaf(bf2f(u3.x), w3, a0); a1 = fmaf(bf2f(u3.y), w3, a1);
      a2 = fmaf(bf2f(u3.z), w3, a2); a3 = fmaf(bf2f(u3.w), w3, a3);
      if constexpr (!PASS_B) sw += (w0 + w1) + (w2 + w3);
    }
    for (; j < end; ++j) {
      const int2 p = csr[j];
      const ushort4 u =
          *reinterpret_cast<const ushort4*>(h + (long long)p.x * 64 + sl * 4);
      const float w = __int_as_float(p.y);
      a0 = fmaf(bf2f(u.x), w, a0); a1 = fmaf(bf2f(u.y), w, a1);
      a2 = fmaf(bf2f(u.z), w, a2); a3 = fmaf(bf2f(u.w), w, a3);
      if constexpr (!PASS_B) sw += w;
    }
    if constexpr (!PASS_B) {
      if (sl == 0) s_out[n] = sw;
      ushort4 o;
      o.x = f2bf(a0); o.y = f2bf(a1); o.z = f2bf(a2); o.w = f2bf(a3);
      *reinterpret_cast<ushort4*>(out + (long long)n * 64 + sl * 4) = o;
    } else {
      const float si = s_in[n];
      ushort4 o;
      o.x = f2bf(fmaf(si, bv0, a0 + bb0));
      o.y = f2bf(fmaf(si, bv1, a1 + bb1));
      o.z = f2bf(fmaf(si, bv2, a2 + bb2));
      o.w = f2bf(fmaf(si, bv3, a3 + bb3));
      *reinterpret_cast<ushort4*>(out + (long long)n * 64 + sl * 4) = o;
    }
  }
}

extern "C" void kernel_launch(void* const* d_in, const int* in_sizes, int n_in,
                              void* d_out, int out_size, void* d_ws,
                              size_t ws_size, hipStream_t stream) {
  const float* x_self = (const float*)d_in[0];
  const float* x_nb = (const float*)d_in[1];
  const int* ei = (const int*)d_in[2];
  const float* Wis = (const float*)d_in[3];
  const float* bis = (const float*)d_in[4];
  const float* Wos = (const float*)d_in[5];
  const float* bos = (const float*)d_in[6];
  const float* Wg1 = (const float*)d_in[7];
  const float* bg1 = (const float*)d_in[8];
  const float* Wg2 = (const float*)d_in[9];
  const float* bg2 = (const float*)d_in[10];
  const float* Wo = (const float*)d_in[11];
  const float* bo = (const float*)d_in[12];

  const int N = in_sizes[0] / 128;
  const int E = (int)(in_sizes[2] / 2);
  const int* rows = ei;
  const int* cols = ei + E;

  float* out1 = (float*)d_out;
  float* out2 = out1 + (long long)N * 64;

  // ws (4B units): dis[N] | deg[N] | off[N+16] | part[64] | s[N] |
  //   W12f[8192] | bvec[64] | csr int2[E] | S1 bf16[N*128] | S2 bf16[N*128] |
  //   S3 bf16[N*64] | P bf16[53248]
  float* dis = (float*)d_ws;
  int* deg = (int*)(dis + N);
  int* off = deg + N;
  int* part = off + N + 16;
  float* s = (float*)(part + 64);
  float* W12f = s + N;
  float* bvec = W12f + 8192;
  int2* csr = (int2*)(bvec + 64);
  unsigned short* S1 = (unsigned short*)(csr + E);
  unsigned short* S2 = S1 + (long long)N * 128;
  unsigned short* S3 = S2 + (long long)N * 128;
  unsigned short* P = S3 + (long long)N * 64;
  unsigned short* pWis = P + 0;
  unsigned short* pWos0 = P + 16384;
  unsigned short* pWos1 = P + 24576;
  unsigned short* pWo0 = P + 32768;
  unsigned short* pWo1 = P + 40960;
  unsigned short* pW12 = P + 45056;

  const int NB = (N + 1023) / 1024;
  const int GB = N / 64;            // 625
  const int GGB = (N + 15) / 16;    // 2500 gather blocks: 1 node per 16-lane group

  // --- CSR build + norms ---
  zero_kernel<<<(N + 255) / 256, 256, 0, stream>>>(deg, N);
  deg_kernel<<<(E + 255) / 256, 256, 0, stream>>>(cols, deg, E);
  scan1_kernel<<<NB, 1024, 0, stream>>>(deg, off, part, dis, N);
  scan3_kernel<<<NB, 1024, 0, stream>>>(off, part, N);
  fill_kernel<<<(E + 255) / 256, 256, 0, stream>>>(rows, cols, off, dis, csr, E);

  // --- conversions + weight prep ---
  cvt_kernel<<<(N * 32 + 255) / 256, 256, 0, stream>>>(x_self, S1, N * 32);
  w12_kernel<<<33, 256, 0, stream>>>(Wg1, Wg2, bg1, W12f, bvec);
  pack_all_kernel<<<26, 256, 0, stream>>>(Wis, Wos, Wo, W12f, P);

  // --- self branch ---
  mfma_gemm_kernel<128, 0, 128, true, true, false>
      <<<GB, 256, 0, stream>>>(S1, nullptr, pWis, nullptr, bis, S2);
  mfma_gemm_kernel<128, 128, 64, false, false, false>
      <<<GB, 256, 0, stream>>>(S1, S2, pWos0, pWos1, bos, out1);

  // --- GCN branch: g2 = A·(A·(X·W12)) + s·(bg1·Wg2) + bg2 ---
  mfma_gemm_kernel<128, 0, 64, false, true, false>
      <<<GB, 256, 0, stream>>>(S1, nullptr, pW12, nullptr, nullptr, S2);
  gather64_kernel<false><<<GGB, 256, 0, stream>>>(
      S2, csr, off, dis, s, nullptr, nullptr, nullptr, S3, N);
  gather64_kernel<true><<<GGB, 256, 0, stream>>>(
      S3, csr, off, dis, nullptr, s, bvec, bg2, S1, N);
  mfma_gemm_kernel<128, 64, 64, false, false, true>
      <<<GB, 256, 0, stream>>>(x_nb, S1, pWo0, pWo1, bo, out2);
}